// Round 3
// baseline (327.846 us; speedup 1.0000x reference)
//
#include <hip/hip_runtime.h>
#include <hip/hip_bf16.h>

#define MDIM 4096
#define DDIM 2048
#define HDIM 2048
#define EDIM 8

typedef float v4f __attribute__((ext_vector_type(4)));
typedef int   v4i __attribute__((ext_vector_type(4)));
typedef int   v8i __attribute__((ext_vector_type(8)));

// async global->LDS, 16B per lane. lds pointer must be wave-uniform
// (HW writes base + lane*16).
__device__ __forceinline__ void gl2lds16(const void* g, void* l) {
  __builtin_amdgcn_global_load_lds(
      (const __attribute__((address_space(1))) void*)g,
      (__attribute__((address_space(3))) void*)l,
      16, 0, 0);
}

// ---------------- Kernel 1: gating softmax + fp8 quantize of x ----------------
__global__ __launch_bounds__(256) void k_gate_xq(
    const float* __restrict__ x, const float* __restrict__ gw,
    const float* __restrict__ gb, float* __restrict__ gate,
    unsigned char* __restrict__ x8)
{
  const int wid  = threadIdx.x >> 6;
  const int lane = threadIdx.x & 63;
  const int m    = blockIdx.x * 4 + wid;

  const float4* xr = (const float4*)(x + (size_t)m * DDIM);
  unsigned int* qr = (unsigned int*)(x8 + (size_t)m * DDIM);

  float part[EDIM];
#pragma unroll
  for (int e = 0; e < EDIM; ++e) part[e] = 0.f;

#pragma unroll
  for (int it = 0; it < DDIM / 4 / 64; ++it) {   // 8 iterations
    const int idx = it * 64 + lane;
    const float4 xv = xr[idx];
    int pk = __builtin_amdgcn_cvt_pk_fp8_f32(xv.x, xv.y, 0, false);
    pk = __builtin_amdgcn_cvt_pk_fp8_f32(xv.z, xv.w, pk, true);
    qr[idx] = (unsigned int)pk;
#pragma unroll
    for (int e = 0; e < EDIM; ++e) {
      const float4 wv = ((const float4*)(gw + (size_t)e * DDIM))[idx];
      part[e] += xv.x * wv.x + xv.y * wv.y + xv.z * wv.z + xv.w * wv.w;
    }
  }
#pragma unroll
  for (int e = 0; e < EDIM; ++e) {
#pragma unroll
    for (int off = 32; off > 0; off >>= 1)
      part[e] += __shfl_xor(part[e], off);
  }
  float lg[EDIM];
  float s = 0.f;
#pragma unroll
  for (int e = 0; e < EDIM; ++e) lg[e] = part[e] + gb[e];
  float mx = lg[0];
#pragma unroll
  for (int e = 1; e < EDIM; ++e) mx = fmaxf(mx, lg[e]);
#pragma unroll
  for (int e = 0; e < EDIM; ++e) { lg[e] = expf(lg[e] - mx); s += lg[e]; }
  const float inv = 1.f / s;
  if (lane < EDIM) gate[m * EDIM + lane] = lg[lane] * inv;
}

// ---------------- Kernel 2: fp8 quantize of expert_w --------------------------
__global__ void k_wq(const float* __restrict__ w, unsigned char* __restrict__ w8)
{
  const long long n4 = (long long)EDIM * HDIM * DDIM / 4;
  const long long stride = (long long)gridDim.x * blockDim.x;
  for (long long i = (long long)blockIdx.x * blockDim.x + threadIdx.x; i < n4;
       i += stride) {
    const float4 v = ((const float4*)w)[i];
    int pk = __builtin_amdgcn_cvt_pk_fp8_f32(v.x, v.y, 0, false);
    pk = __builtin_amdgcn_cvt_pk_fp8_f32(v.z, v.w, pk, true);
    ((unsigned int*)w8)[i] = (unsigned int)pk;
  }
}

// ---------------- Kernel 3: fused grouped GEMM + gated combine ----------------
// Block = 256 threads (4 waves, 2x2), tile 128x128, BK = 128 fp8 bytes.
// MX-scaled MFMA (16x16x128 f8f6f4, fp8/fp8, unit e8m0 scales = 127): exact
// same fp8 products as the non-scaled path, at 2x matrix-pipe rate.
// T2 XOR-swizzle (rule #21): LDS dest linear, global SOURCE inverse-swizzled,
// ds_read applies the same involution. C/D layout of 16x16x128 == 16x16x32,
// so the gated-combine epilogue is unchanged.
__global__ __launch_bounds__(256, 2) void k_moe_gemm(
    const unsigned char* __restrict__ x8,   // [M, D]
    const unsigned char* __restrict__ w8,   // [E, H, D]
    const float* __restrict__ gate,         // [M, 8]
    float* __restrict__ out)                // [M, H] f32
{
  __shared__ __align__(16) unsigned char sA[128 * 128];
  __shared__ __align__(16) unsigned char sB[128 * 128];

  const int tid  = threadIdx.x;
  const int lane = tid & 63;
  const int wid  = tid >> 6;
  const int wm   = wid >> 1;        // 0..1
  const int wn   = wid & 1;         // 0..1
  const int bm   = blockIdx.y * 128;
  const int bn   = blockIdx.x * 128;
  const int lrow = lane & 15;
  const int lk   = lane >> 4;       // 0..3 -> k-block of 32 bytes
  const int swz  = (lrow & 7) << 4; // read-side XOR (row&7 == lrow&7 here)
  const int c0   = (lk * 32) ^ swz;       // first 16B chunk (swizzled)
  const int c1   = (lk * 32 + 16) ^ swz;  // second 16B chunk (swizzled)

  v4f outacc[4][4];
#pragma unroll
  for (int i = 0; i < 4; ++i)
#pragma unroll
    for (int j = 0; j < 4; ++j) {
      outacc[i][j][0] = 0.f; outacc[i][j][1] = 0.f;
      outacc[i][j][2] = 0.f; outacc[i][j][3] = 0.f;
    }

  for (int e = 0; e < EDIM; ++e) {
    const unsigned char* wb = w8 + (size_t)e * HDIM * DDIM;
    v4f acc[4][4];
#pragma unroll
    for (int i = 0; i < 4; ++i)
#pragma unroll
      for (int j = 0; j < 4; ++j) {
        acc[i][j][0] = 0.f; acc[i][j][1] = 0.f;
        acc[i][j][2] = 0.f; acc[i][j][3] = 0.f;
      }

    for (int kt = 0; kt < DDIM / 128; ++kt) {
      const int k0 = kt * 128;
      // stage 16KB A-tile + 16KB B-tile (4 x 1KB per wave each)
#pragma unroll
      for (int i = 0; i < 4; ++i) {
        const int p   = i * 4096 + tid * 16;
        const int row = p >> 7;                          // 0..127
        const int col = (p & 127) ^ ((row & 7) << 4);    // inverse-swz source
        void* ldsu = (void*)(sA + i * 4096 + wid * 1024);  // wave-uniform
        gl2lds16(x8 + (size_t)(bm + row) * DDIM + k0 + col, ldsu);
        void* ldsv = (void*)(sB + i * 4096 + wid * 1024);
        gl2lds16(wb + (size_t)(bn + row) * DDIM + k0 + col, ldsv);
      }
      __syncthreads();

      // A fragments: lane holds A[row=lrow][k = lk*32 .. +31] (32 bytes)
      v8i av[4];
#pragma unroll
      for (int f = 0; f < 4; ++f) {
        const unsigned char* pa =
            sA + (size_t)(wm * 64 + f * 16 + lrow) * 128;
        union { v8i v; v4i h[2]; } u;
        u.h[0] = *(const v4i*)(pa + c0);
        u.h[1] = *(const v4i*)(pa + c1);
        av[f] = u.v;
      }
      // B fragments interleaved with MFMA columns (keeps VGPRs < 256)
#pragma unroll
      for (int j = 0; j < 4; ++j) {
        const unsigned char* pb =
            sB + (size_t)(wn * 64 + j * 16 + lrow) * 128;
        union { v8i v; v4i h[2]; } u;
        u.h[0] = *(const v4i*)(pb + c0);
        u.h[1] = *(const v4i*)(pb + c1);
        const v8i bvj = u.v;
#pragma unroll
        for (int i = 0; i < 4; ++i)
          acc[i][j] = __builtin_amdgcn_mfma_scale_f32_16x16x128_f8f6f4(
              av[i], bvj, acc[i][j], 0 /*fp8*/, 0 /*fp8*/,
              0, 127 /*e8m0 1.0*/, 0, 127 /*e8m0 1.0*/);
      }
      __syncthreads();
    }

    // gated combine with bf16 rounding of y (matches reference .astype(bf16))
#pragma unroll
    for (int i = 0; i < 4; ++i) {
      float g[4];
#pragma unroll
      for (int q = 0; q < 4; ++q)
        g[q] = gate[(size_t)(bm + wm * 64 + i * 16 + lk * 4 + q) * EDIM + e];
#pragma unroll
      for (int j = 0; j < 4; ++j)
#pragma unroll
        for (int q = 0; q < 4; ++q) {
          const float yb = __bfloat162float(__float2bfloat16(acc[i][j][q]));
          outacc[i][j][q] += g[q] * yb;
        }
    }
  }

  // write out[m, h] (f32), coalesced across the 16 lanes of each row group
#pragma unroll
  for (int i = 0; i < 4; ++i)
#pragma unroll
    for (int q = 0; q < 4; ++q) {
      const size_t r = (size_t)(bm + wm * 64 + i * 16 + lk * 4 + q);
      float* orow = out + r * HDIM + bn + wn * 64 + lrow;
#pragma unroll
      for (int j = 0; j < 4; ++j)
        orow[j * 16] = outacc[i][j][q];
    }
}

extern "C" void kernel_launch(void* const* d_in, const int* in_sizes, int n_in,
                              void* d_out, int out_size, void* d_ws, size_t ws_size,
                              hipStream_t stream) {
  (void)in_sizes; (void)n_in; (void)out_size; (void)ws_size;
  const float* x        = (const float*)d_in[0];
  const float* gate_w   = (const float*)d_in[1];
  const float* gate_b   = (const float*)d_in[2];
  const float* expert_w = (const float*)d_in[3];
  float* out = (float*)d_out;

  char* ws = (char*)d_ws;
  float* gate       = (float*)ws;                                   // 131072 B
  unsigned char* x8 = (unsigned char*)(ws + 131072);                // 8 MiB
  unsigned char* w8 = (unsigned char*)(ws + 131072 + (size_t)MDIM * DDIM);

  hipLaunchKernelGGL(k_gate_xq, dim3(MDIM / 4), dim3(256), 0, stream,
                     x, gate_w, gate_b, gate, x8);
  hipLaunchKernelGGL(k_wq, dim3(4096), dim3(256), 0, stream, expert_w, w8);
  hipLaunchKernelGGL(k_moe_gemm, dim3(HDIM / 128, MDIM / 128), dim3(256), 0,
                     stream, x8, w8, gate, out);
}

// Round 4
// 182.850 us; speedup vs baseline: 1.7930x; 1.7930x over previous
//
#include <hip/hip_runtime.h>
#include <hip/hip_bf16.h>

#define MDIM 4096
#define DDIM 2048
#define HDIM 2048
#define EDIM 8

typedef float v4f __attribute__((ext_vector_type(4)));
typedef int   v4i __attribute__((ext_vector_type(4)));
typedef int   v8i __attribute__((ext_vector_type(8)));

// async global->LDS, 16B per lane. lds pointer must be wave-uniform
// (HW writes base + lane*16).
__device__ __forceinline__ void gl2lds16(const void* g, void* l) {
  __builtin_amdgcn_global_load_lds(
      (const __attribute__((address_space(1))) void*)g,
      (__attribute__((address_space(3))) void*)l,
      16, 0, 0);
}

// ---------------- Kernel 1: gating softmax + fp8 quantize of x ----------------
__global__ __launch_bounds__(256) void k_gate_xq(
    const float* __restrict__ x, const float* __restrict__ gw,
    const float* __restrict__ gb, float* __restrict__ gate,
    unsigned char* __restrict__ x8)
{
  const int wid  = threadIdx.x >> 6;
  const int lane = threadIdx.x & 63;
  const int m    = blockIdx.x * 4 + wid;

  const float4* xr = (const float4*)(x + (size_t)m * DDIM);
  unsigned int* qr = (unsigned int*)(x8 + (size_t)m * DDIM);

  float part[EDIM];
#pragma unroll
  for (int e = 0; e < EDIM; ++e) part[e] = 0.f;

#pragma unroll
  for (int it = 0; it < DDIM / 4 / 64; ++it) {   // 8 iterations
    const int idx = it * 64 + lane;
    const float4 xv = xr[idx];
    int pk = __builtin_amdgcn_cvt_pk_fp8_f32(xv.x, xv.y, 0, false);
    pk = __builtin_amdgcn_cvt_pk_fp8_f32(xv.z, xv.w, pk, true);
    qr[idx] = (unsigned int)pk;
#pragma unroll
    for (int e = 0; e < EDIM; ++e) {
      const float4 wv = ((const float4*)(gw + (size_t)e * DDIM))[idx];
      part[e] += xv.x * wv.x + xv.y * wv.y + xv.z * wv.z + xv.w * wv.w;
    }
  }
#pragma unroll
  for (int e = 0; e < EDIM; ++e) {
#pragma unroll
    for (int off = 32; off > 0; off >>= 1)
      part[e] += __shfl_xor(part[e], off);
  }
  float lg[EDIM];
  float s = 0.f;
#pragma unroll
  for (int e = 0; e < EDIM; ++e) lg[e] = part[e] + gb[e];
  float mx = lg[0];
#pragma unroll
  for (int e = 1; e < EDIM; ++e) mx = fmaxf(mx, lg[e]);
#pragma unroll
  for (int e = 0; e < EDIM; ++e) { lg[e] = expf(lg[e] - mx); s += lg[e]; }
  const float inv = 1.f / s;
  if (lane < EDIM) gate[m * EDIM + lane] = lg[lane] * inv;
}

// ---------------- Kernel 2: fp8 quantize of expert_w --------------------------
__global__ void k_wq(const float* __restrict__ w, unsigned char* __restrict__ w8)
{
  const long long n4 = (long long)EDIM * HDIM * DDIM / 4;
  const long long stride = (long long)gridDim.x * blockDim.x;
  for (long long i = (long long)blockIdx.x * blockDim.x + threadIdx.x; i < n4;
       i += stride) {
    const float4 v = ((const float4*)w)[i];
    int pk = __builtin_amdgcn_cvt_pk_fp8_f32(v.x, v.y, 0, false);
    pk = __builtin_amdgcn_cvt_pk_fp8_f32(v.z, v.w, pk, true);
    ((unsigned int*)w8)[i] = (unsigned int)pk;
  }
}

// ---------------- Kernel 3: fused grouped GEMM + gated combine ----------------
// Block = 256 threads (4 waves, 2x2), tile 128x128, BK = 128 fp8 bytes.
// MX-scaled MFMA (16x16x128 f8f6f4, fp8/fp8, unit e8m0 scales = 127).
// T2 XOR-swizzle both-sides (source inverse-swz, read swz, LDS dest linear).
// T3-minimum 2-phase: double-buffered LDS; STAGE(t+1) issued BEFORE the
// ds_read+MFMA of tile t, so the single vmcnt(0)-drain per tile waits on
// loads that had a full compute phase in flight.
// T1 XCD swizzle: each XCD owns an 8x8 tile square -> per-K-step working set
// across an XCD is ~256KB -> staging loads hit L2.
__global__ __launch_bounds__(256, 2) void k_moe_gemm(
    const unsigned char* __restrict__ x8,   // [M, D]
    const unsigned char* __restrict__ w8,   // [E, H, D]
    const float* __restrict__ gate,         // [M, 8]
    float* __restrict__ out)                // [M, H] f32
{
  __shared__ __align__(16) unsigned char sA[2 * 16384];
  __shared__ __align__(16) unsigned char sB[2 * 16384];

  const int tid  = threadIdx.x;
  const int lane = tid & 63;
  const int wid  = tid >> 6;
  const int wm   = wid >> 1;        // 0..1
  const int wn   = wid & 1;         // 0..1

  // XCD-aware 2-D chunking: 512 blocks, xcd = bid&7, each XCD gets an
  // 8x8 square of (m,h) tiles (bijective: 4 m-chunks x 2 h-chunks).
  const int bid   = blockIdx.x;
  const int xcd   = bid & 7;
  const int local = bid >> 3;                 // 0..63
  const int tm    = (xcd >> 1) * 8 + (local >> 3);   // 0..31
  const int tn    = (xcd & 1) * 8 + (local & 7);     // 0..15
  const int bm    = tm * 128;
  const int bn    = tn * 128;

  const int lrow = lane & 15;
  const int lk   = lane >> 4;       // 0..3 -> k-block of 32 bytes
  const int swz  = (lrow & 7) << 4; // read-side XOR (row&7 == lrow&7 here)
  const int c0   = (lk * 32) ^ swz;       // first 16B chunk (swizzled)
  const int c1   = (lk * 32 + 16) ^ swz;  // second 16B chunk (swizzled)

  // staging source coordinates (per thread, fixed across iterations)
  const int srow[4] = {(0 * 4096 + tid * 16) >> 7, (1 * 4096 + tid * 16) >> 7,
                       (2 * 4096 + tid * 16) >> 7, (3 * 4096 + tid * 16) >> 7};
  const int scol[4] = {
      ((0 * 4096 + tid * 16) & 127) ^ ((srow[0] & 7) << 4),
      ((1 * 4096 + tid * 16) & 127) ^ ((srow[1] & 7) << 4),
      ((2 * 4096 + tid * 16) & 127) ^ ((srow[2] & 7) << 4),
      ((3 * 4096 + tid * 16) & 127) ^ ((srow[3] & 7) << 4)};

  v4f outacc[4][4];
  v4f acc[4][4];
#pragma unroll
  for (int i = 0; i < 4; ++i)
#pragma unroll
    for (int j = 0; j < 4; ++j) {
      outacc[i][j][0] = 0.f; outacc[i][j][1] = 0.f;
      outacc[i][j][2] = 0.f; outacc[i][j][3] = 0.f;
      acc[i][j][0] = 0.f; acc[i][j][1] = 0.f;
      acc[i][j][2] = 0.f; acc[i][j][3] = 0.f;
    }

  // ---- prologue: stage tile it=0 into buffer 0
  {
#pragma unroll
    for (int i = 0; i < 4; ++i) {
      gl2lds16(x8 + (size_t)(bm + srow[i]) * DDIM + scol[i],
               (void*)(sA + i * 4096 + wid * 1024));
      gl2lds16(w8 + (size_t)(bn + srow[i]) * DDIM + scol[i],
               (void*)(sB + i * 4096 + wid * 1024));
    }
  }
  __syncthreads();

  // ---- main loop: it = e*16 + kt, 128 tiles, 2-phase dbuf
#define MOE_STEP(IT, RB, SB)                                                   \
  {                                                                            \
    const int itn = (IT) + 1;                                                  \
    if (itn < 128) {                                                           \
      const unsigned char* wbe =                                               \
          w8 + (size_t)(itn >> 4) * ((size_t)HDIM * DDIM);                     \
      const int k0n = (itn & 15) * 128;                                        \
      _Pragma("unroll") for (int i = 0; i < 4; ++i) {                          \
        gl2lds16(x8 + (size_t)(bm + srow[i]) * DDIM + k0n + scol[i],           \
                 (void*)(sA + (SB) * 16384 + i * 4096 + wid * 1024));          \
        gl2lds16(wbe + (size_t)(bn + srow[i]) * DDIM + k0n + scol[i],          \
                 (void*)(sB + (SB) * 16384 + i * 4096 + wid * 1024));          \
      }                                                                        \
    }                                                                          \
    const unsigned char* pA = sA + (RB) * 16384;                               \
    const unsigned char* pB = sB + (RB) * 16384;                               \
    v8i av[4];                                                                 \
    _Pragma("unroll") for (int f = 0; f < 4; ++f) {                            \
      const unsigned char* pa = pA + (size_t)(wm * 64 + f * 16 + lrow) * 128;  \
      union { v8i v; v4i h[2]; } u;                                            \
      u.h[0] = *(const v4i*)(pa + c0);                                         \
      u.h[1] = *(const v4i*)(pa + c1);                                         \
      av[f] = u.v;                                                             \
    }                                                                          \
    _Pragma("unroll") for (int j = 0; j < 4; ++j) {                            \
      const unsigned char* pb = pB + (size_t)(wn * 64 + j * 16 + lrow) * 128;  \
      union { v8i v; v4i h[2]; } u;                                            \
      u.h[0] = *(const v4i*)(pb + c0);                                         \
      u.h[1] = *(const v4i*)(pb + c1);                                         \
      const v8i bvj = u.v;                                                     \
      _Pragma("unroll") for (int i = 0; i < 4; ++i)                            \
        acc[i][j] = __builtin_amdgcn_mfma_scale_f32_16x16x128_f8f6f4(          \
            av[i], bvj, acc[i][j], 0 /*fp8*/, 0 /*fp8*/,                       \
            0, 127 /*e8m0 1.0*/, 0, 127 /*e8m0 1.0*/);                         \
    }                                                                          \
    if (((IT) & 15) == 15) {                                                   \
      const int e = (IT) >> 4;                                                 \
      _Pragma("unroll") for (int i = 0; i < 4; ++i) {                          \
        float g[4];                                                            \
        _Pragma("unroll") for (int q = 0; q < 4; ++q)                          \
          g[q] =                                                               \
              gate[(size_t)(bm + wm * 64 + i * 16 + lk * 4 + q) * EDIM + e];   \
        _Pragma("unroll") for (int j = 0; j < 4; ++j)                          \
          _Pragma("unroll") for (int q = 0; q < 4; ++q) {                      \
            const float yb = __bfloat162float(__float2bfloat16(acc[i][j][q])); \
            outacc[i][j][q] += g[q] * yb;                                      \
            acc[i][j][q] = 0.f;                                                \
          }                                                                    \
      }                                                                        \
    }                                                                          \
    __syncthreads();                                                           \
  }

  for (int it = 0; it < 128; it += 2) {
    MOE_STEP(it, 0, 1);
    MOE_STEP(it + 1, 1, 0);
  }
#undef MOE_STEP

  // write out[m, h] (f32), coalesced across the 16 lanes of each row group
#pragma unroll
  for (int i = 0; i < 4; ++i)
#pragma unroll
    for (int q = 0; q < 4; ++q) {
      const size_t r = (size_t)(bm + wm * 64 + i * 16 + lk * 4 + q);
      float* orow = out + r * HDIM + bn + wn * 64 + lrow;
#pragma unroll
      for (int j = 0; j < 4; ++j)
        orow[j * 16] = outacc[i][j][q];
    }
}

extern "C" void kernel_launch(void* const* d_in, const int* in_sizes, int n_in,
                              void* d_out, int out_size, void* d_ws, size_t ws_size,
                              hipStream_t stream) {
  (void)in_sizes; (void)n_in; (void)out_size; (void)ws_size;
  const float* x        = (const float*)d_in[0];
  const float* gate_w   = (const float*)d_in[1];
  const float* gate_b   = (const float*)d_in[2];
  const float* expert_w = (const float*)d_in[3];
  float* out = (float*)d_out;

  char* ws = (char*)d_ws;
  float* gate       = (float*)ws;                                   // 131072 B
  unsigned char* x8 = (unsigned char*)(ws + 131072);                // 8 MiB
  unsigned char* w8 = (unsigned char*)(ws + 131072 + (size_t)MDIM * DDIM);

  hipLaunchKernelGGL(k_gate_xq, dim3(MDIM / 4), dim3(256), 0, stream,
                     x, gate_w, gate_b, gate, x8);
  hipLaunchKernelGGL(k_wq, dim3(4096), dim3(256), 0, stream, expert_w, w8);
  hipLaunchKernelGGL(k_moe_gemm, dim3(512), dim3(256), 0, stream,
                     x8, w8, gate, out);
}